// Round 10
// baseline (645.869 us; speedup 1.0000x reference)
//
#include <hip/hip_runtime.h>
#include <hip/hip_bf16.h>

#define S_SEQ 8192
#define D_DIM 1024
#define NCLS 7

typedef __bf16 bf16x8 __attribute__((ext_vector_type(8)));
typedef float f32x4 __attribute__((ext_vector_type(4)));

typedef const __attribute__((address_space(1))) void* gas_ptr;
typedef __attribute__((address_space(3))) void* las_ptr;
#define GLL(gp, lp) __builtin_amdgcn_global_load_lds((gas_ptr)(const void*)(gp), (las_ptr)(void*)(lp), 16, 0, 0)

__device__ __forceinline__ unsigned short f2bf(float f) {
    unsigned int u = __builtin_bit_cast(unsigned int, f);
    u = (u + 0x7FFFu + ((u >> 16) & 1u)) >> 16;
    return (unsigned short)u;
}
__device__ __forceinline__ float bf2f(unsigned short h) {
    unsigned int u = ((unsigned int)h) << 16;
    return __builtin_bit_cast(float, u);
}

// ---------------- elementwise fp32 -> bf16 ----------------
__global__ __launch_bounds__(256) void k_f32_to_bf16(const float* __restrict__ src,
                                                     unsigned short* __restrict__ dst, int n4) {
    int i = blockIdx.x * 256 + threadIdx.x;
    if (i >= n4) return;
    float4 v = ((const float4*)src)[i];
    ushort4 o;
    o.x = f2bf(v.x); o.y = f2bf(v.y); o.z = f2bf(v.z); o.w = f2bf(v.w);
    ((ushort4*)dst)[i] = o;
}

// ---------------- sum of two fp32 arrays -> bf16 ----------------
__global__ __launch_bounds__(256) void k_sum2_bf16(const float* __restrict__ a,
                                                   const float* __restrict__ b,
                                                   unsigned short* __restrict__ dst, int n4) {
    int i = blockIdx.x * 256 + threadIdx.x;
    if (i >= n4) return;
    float4 va = ((const float4*)a)[i];
    float4 vb = ((const float4*)b)[i];
    ushort4 o;
    o.x = f2bf(va.x + vb.x); o.y = f2bf(va.y + vb.y);
    o.z = f2bf(va.z + vb.z); o.w = f2bf(va.w + vb.w);
    ((ushort4*)dst)[i] = o;
}

// ---------------- concat 3 bias vectors [1024] -> [3072] ----------------
__global__ __launch_bounds__(256) void k_concat3(const float* __restrict__ a,
                                                 const float* __restrict__ b,
                                                 const float* __restrict__ c,
                                                 float* __restrict__ out) {
    int i = blockIdx.x * 256 + threadIdx.x;
    float v = (i < 1024) ? a[i] : (i < 2048) ? b[i - 1024] : c[i - 2048];
    out[i] = v;
}

// ------- fused transpose of 4 weight matrices: fp32 [K][N] -> bf16 [N][K] -------
__global__ __launch_bounds__(256) void k_transpose4(const float* __restrict__ W0,
                                                    const float* __restrict__ W1,
                                                    const float* __restrict__ W2,
                                                    const float* __restrict__ W3,
                                                    unsigned short* __restrict__ dqkv,
                                                    unsigned short* __restrict__ dsto) {
    __shared__ unsigned short t[64][80];
    const float* srcs[4] = {W0, W1, W2, W3};
    const int z = blockIdx.z;
    const float* src = srcs[z];
    unsigned short* dst = (z < 3) ? (dqkv + (size_t)z * D_DIM * D_DIM) : dsto;
    const int C = D_DIM, R = D_DIM;
    int r0 = blockIdx.x * 64, c0 = blockIdx.y * 64;
    int tid = threadIdx.x;
    int rr = tid >> 4, cc = (tid & 15) << 2;
#pragma unroll
    for (int p = 0; p < 4; ++p) {
        int r = rr + p * 16;
        float4 v = *(const float4*)(src + (size_t)(r0 + r) * C + c0 + cc);
        t[cc + 0][r] = f2bf(v.x);
        t[cc + 1][r] = f2bf(v.y);
        t[cc + 2][r] = f2bf(v.z);
        t[cc + 3][r] = f2bf(v.w);
    }
    __syncthreads();
    int wr = tid >> 3, wc = (tid & 7) << 3;
#pragma unroll
    for (int p = 0; p < 2; ++p) {
        int c = wr + p * 32;
        uint4 v8 = *(const uint4*)&t[c][wc];
        *(uint4*)(dst + (size_t)(c0 + c) * R + r0 + wc) = v8;
    }
}

// ---- LN apply (q,k) + V-stat store ----
__global__ __launch_bounds__(256) void k_ln_apply_qk(const unsigned short* __restrict__ zb,
                                                     const float* __restrict__ pS,
                                                     const float* __restrict__ pQ,
                                                     const float* __restrict__ gq, const float* __restrict__ betaq,
                                                     const float* __restrict__ gk, const float* __restrict__ betak,
                                                     unsigned short* __restrict__ qb,
                                                     unsigned short* __restrict__ kb,
                                                     float* __restrict__ vstat) {
    __shared__ float sS[48], sQ[48];
    int row = blockIdx.x, tid = threadIdx.x;
    if (tid < 48) { sS[tid] = pS[(size_t)row * 48 + tid]; sQ[tid] = pQ[(size_t)row * 48 + tid]; }
    __syncthreads();
    float m[3], rs[3];
#pragma unroll
    for (int c = 0; c < 3; ++c) {
        float s = 0.0f, q = 0.0f;
#pragma unroll
        for (int j = 0; j < 16; ++j) { s += sS[c * 16 + j]; q += sQ[c * 16 + j]; }
        float mm = s * (1.0f / D_DIM);
        float var = q * (1.0f / D_DIM) - mm * mm;
        m[c] = mm; rs[c] = rsqrtf(var + 1e-5f);
    }
    if (tid == 0) { vstat[2 * row] = m[2]; vstat[2 * row + 1] = rs[2]; }
    const unsigned short* zrow = zb + (size_t)row * 3072;
    {
        ushort4 u = *(const ushort4*)(zrow + tid * 4);
        float4 g4 = *(const float4*)(gq + tid * 4);
        float4 b4 = *(const float4*)(betaq + tid * 4);
        ushort4 o;
        o.x = f2bf((bf2f(u.x) - m[0]) * rs[0] * g4.x + b4.x);
        o.y = f2bf((bf2f(u.y) - m[0]) * rs[0] * g4.y + b4.y);
        o.z = f2bf((bf2f(u.z) - m[0]) * rs[0] * g4.z + b4.z);
        o.w = f2bf((bf2f(u.w) - m[0]) * rs[0] * g4.w + b4.w);
        *(ushort4*)(qb + (size_t)row * D_DIM + tid * 4) = o;
    }
    {
        ushort4 u = *(const ushort4*)(zrow + 1024 + tid * 4);
        float4 g4 = *(const float4*)(gk + tid * 4);
        float4 b4 = *(const float4*)(betak + tid * 4);
        ushort4 o;
        o.x = f2bf((bf2f(u.x) - m[1]) * rs[1] * g4.x + b4.x);
        o.y = f2bf((bf2f(u.y) - m[1]) * rs[1] * g4.y + b4.y);
        o.z = f2bf((bf2f(u.z) - m[1]) * rs[1] * g4.z + b4.z);
        o.w = f2bf((bf2f(u.w) - m[1]) * rs[1] * g4.w + b4.w);
        *(ushort4*)(kb + (size_t)row * D_DIM + tid * 4) = o;
    }
}

// ---- LN-V + transpose: zb V-slice -> Vt ----
__global__ __launch_bounds__(256) void k_transpose_lnv(const unsigned short* __restrict__ zb,
                                                       const float* __restrict__ vstat,
                                                       const float* __restrict__ gv,
                                                       const float* __restrict__ betav,
                                                       unsigned short* __restrict__ Vt) {
    __shared__ unsigned short t[64][80];
    int s0 = blockIdx.x * 64, d0 = blockIdx.y * 64;
    int tid = threadIdx.x;
    int rr = tid >> 3, cc = (tid & 7) << 3;
    float4 g0 = *(const float4*)(gv + d0 + cc);
    float4 g1 = *(const float4*)(gv + d0 + cc + 4);
    float4 b0 = *(const float4*)(betav + d0 + cc);
    float4 b1 = *(const float4*)(betav + d0 + cc + 4);
    float gg[8] = {g0.x, g0.y, g0.z, g0.w, g1.x, g1.y, g1.z, g1.w};
    float bb[8] = {b0.x, b0.y, b0.z, b0.w, b1.x, b1.y, b1.z, b1.w};
#pragma unroll
    for (int p = 0; p < 2; ++p) {
        int r = rr + p * 32;
        float m = vstat[2 * (s0 + r)], rs = vstat[2 * (s0 + r) + 1];
        uint4 u = *(const uint4*)(zb + (size_t)(s0 + r) * 3072 + 2048 + d0 + cc);
        const unsigned short* pu = (const unsigned short*)&u;
#pragma unroll
        for (int i = 0; i < 8; ++i)
            t[cc + i][r] = f2bf((bf2f(pu[i]) - m) * rs * gg[i] + bb[i]);
    }
    __syncthreads();
    int wr = tid >> 3, wc = (tid & 7) << 3;
#pragma unroll
    for (int p = 0; p < 2; ++p) {
        int c = wr + p * 32;
        uint4 v8 = *(const uint4*)&t[c][wc];
        *(uint4*)(Vt + (size_t)(d0 + c) * S_SEQ + s0 + wc) = v8;
    }
}

// ---------------- combine per-tile stats ----------------
__global__ __launch_bounds__(256) void k_stats_reduce(const float* __restrict__ pmax,
                                                      const float* __restrict__ psum,
                                                      float* __restrict__ rmax,
                                                      float* __restrict__ rrecip, int nblk) {
    int row = blockIdx.x * 4 + (threadIdx.x >> 6);
    int lane = threadIdx.x & 63;
    const float* pm = pmax + (size_t)row * nblk;
    const float* ps = psum + (size_t)row * nblk;
    float m = -3.4e38f;
    for (int j = lane; j < nblk; j += 64) m = fmaxf(m, pm[j]);
#pragma unroll
    for (int mk = 32; mk; mk >>= 1) m = fmaxf(m, __shfl_xor(m, mk));
    float s = 0.0f;
    for (int j = lane; j < nblk; j += 64) s += ps[j] * __expf(pm[j] - m);
#pragma unroll
    for (int mk = 32; mk; mk >>= 1) s += __shfl_xor(s, mk);
    if (lane == 0) { rmax[row] = m; rrecip[row] = 1.0f / s; }
}

// ------- normalize: bf16 logits -> fp32 attn + bf16 At -------
__global__ __launch_bounds__(256) void k_norm_transpose(const unsigned short* __restrict__ src16,
                                                        float* __restrict__ attn,
                                                        const float* __restrict__ rmax,
                                                        const float* __restrict__ rrecip,
                                                        unsigned short* __restrict__ At) {
    __shared__ unsigned short t[64][80];
    int t0 = blockIdx.x * 64, s0 = blockIdx.y * 64;
    int tid = threadIdx.x;
    int rr = tid >> 3, cc = (tid & 7) << 3;
#pragma unroll
    for (int p = 0; p < 2; ++p) {
        int r = rr + p * 32;
        float m = rmax[t0 + r], rc = rrecip[t0 + r];
        size_t off = (size_t)(t0 + r) * S_SEQ + s0 + cc;
        uint4 u = *(const uint4*)(src16 + off);
        const unsigned short* pu = (const unsigned short*)&u;
        float v[8];
#pragma unroll
        for (int i = 0; i < 8; ++i) {
            v[i] = __expf(bf2f(pu[i]) - m) * rc;
            t[cc + i][r] = f2bf(v[i]);
        }
        float4 o0 = {v[0], v[1], v[2], v[3]};
        float4 o1 = {v[4], v[5], v[6], v[7]};
        *(float4*)(attn + off) = o0;
        *(float4*)(attn + off + 4) = o1;
    }
    __syncthreads();
    int wr = tid >> 3, wc = (tid & 7) << 3;
#pragma unroll
    for (int p = 0; p < 2; ++p) {
        int c = wr + p * 32;
        uint4 v8 = *(const uint4*)&t[c][wc];
        *(uint4*)(At + (size_t)(s0 + c) * S_SEQ + t0 + wc) = v8;
    }
}

// ---------------- classifier ----------------
__global__ __launch_bounds__(256) void k_classifier(const float* __restrict__ x,
                                                    const float* __restrict__ Wc,
                                                    const float* __restrict__ bc,
                                                    float* __restrict__ outc) {
    __shared__ float red[4][NCLS];
    int row = blockIdx.x, tid = threadIdx.x;
    float4 xv = *(const float4*)(x + (size_t)row * D_DIM + tid * 4);
    const float* w0 = Wc + (size_t)(tid * 4) * NCLS;
    float acc[NCLS];
#pragma unroll
    for (int j = 0; j < NCLS; ++j)
        acc[j] = xv.x * w0[j] + xv.y * w0[NCLS + j] + xv.z * w0[2 * NCLS + j] + xv.w * w0[3 * NCLS + j];
#pragma unroll
    for (int j = 0; j < NCLS; ++j)
#pragma unroll
        for (int o = 32; o; o >>= 1) acc[j] += __shfl_down(acc[j], o);
    int lane = tid & 63, wv = tid >> 6;
    if (lane == 0) {
#pragma unroll
        for (int j = 0; j < NCLS; ++j) red[wv][j] = acc[j];
    }
    __syncthreads();
    if (tid < NCLS) {
        float s = red[0][tid] + red[1][tid] + red[2][tid] + red[3][tid];
        outc[(size_t)row * NCLS + tid] = s + bc[tid];
    }
}

// ======== shared pieces for 8-phase GEMM ========
#define BAR()  __builtin_amdgcn_s_barrier()
#define LGKM0() asm volatile("s_waitcnt lgkmcnt(0)" ::: "memory")
#define VMW(n) asm volatile("s_waitcnt vmcnt(%0)" :: "n"(n) : "memory")

#define AOFF(r, ks) (((r) * 64) + ((((ks) * 32 + g * 8)) ^ (((r) & 7) << 3)))
#define LDA8(sl, q, ii, ks) (*(const bf16x8*)&ldsA[sl][wm][AOFF((q)*32 + (ii)*16 + fm, (ks))])
#define LDB8(db, j, ks) (*(const bf16x8*)&ldsB[db][wn >> 1][AOFF((wn & 1)*64 + (j)*16 + fm, (ks))])

#define MFMA16(q, a00, a10, a01, a11)                                                          \
    {                                                                                          \
        __builtin_amdgcn_s_setprio(1);                                                         \
        _Pragma("unroll")                                                                      \
        for (int j = 0; j < 4; ++j) {                                                          \
            acc[(q)*2 + 0][j] = __builtin_amdgcn_mfma_f32_16x16x32_bf16(a00, breg[j][0], acc[(q)*2 + 0][j], 0, 0, 0); \
            acc[(q)*2 + 1][j] = __builtin_amdgcn_mfma_f32_16x16x32_bf16(a10, breg[j][0], acc[(q)*2 + 1][j], 0, 0, 0); \
            acc[(q)*2 + 0][j] = __builtin_amdgcn_mfma_f32_16x16x32_bf16(a01, breg[j][1], acc[(q)*2 + 0][j], 0, 0, 0); \
            acc[(q)*2 + 1][j] = __builtin_amdgcn_mfma_f32_16x16x32_bf16(a11, breg[j][1], acc[(q)*2 + 1][j], 0, 0, 0); \
        }                                                                                      \
        __builtin_amdgcn_s_setprio(0);                                                         \
    }

// ======== deep-pipelined 8-phase 256x256 GEMM ========
// A: 3 LDS slots (96 KB), B: 2 dbuf (64 KB) = 160 KB. Tile t+2's halves staged during
// tile t's phases -> issue-to-wait distance 5-8 phases; steady-state vmcnt(8) at
// phases 4/8 only. EPI: 0 = fp32 (+bias, SK split C0/C1); 2 = bf16 + softmax stats;
// 3 = bf16 + bias + LN partial stats. Requires M%256==0, N%256==0, (K/SK)%128==0.
template<int SK, int EPI, int USE_NPX>
__global__ __launch_bounds__(512) void k_gemm_8ph(const unsigned short* __restrict__ A,
                                                  const unsigned short* __restrict__ B,
                                                  float* __restrict__ C0,
                                                  float* __restrict__ C1,
                                                  unsigned short* __restrict__ Cb,
                                                  int M, int N, int K, float scale,
                                                  const float* __restrict__ bias,
                                                  float* __restrict__ pS,
                                                  float* __restrict__ pQ) {
    __shared__ unsigned short ldsA[3][2][8192];
    __shared__ unsigned short ldsB[2][2][8192];

    const int tid = threadIdx.x;
    const int lane = tid & 63;
    const int wid = tid >> 6;
    const int wm = wid >> 2;
    const int wn = wid & 3;
    const int fm = lane & 15;
    const int g = lane >> 4;

    const int nbm = M >> 8;
    const int nbn = N >> 8;
    int bm, bn, sk;
    if (USE_NPX && ((nbn & 7) == 0) && ((gridDim.x & 7) == 0)) {
        const int npx = nbn >> 3;
        const int xcd = blockIdx.x & 7;
        const int c = blockIdx.x >> 3;
        bn = xcd * npx + (c % npx);
        const int r2 = c / npx;
        bm = r2 % nbm;
        sk = r2 / nbm;
    } else if ((gridDim.x & 7) == 0) {
        int wg = (blockIdx.x & 7) * (gridDim.x >> 3) + (blockIdx.x >> 3);
        sk = wg / (nbm * nbn);
        int rem = wg % (nbm * nbn);
        bm = rem / nbn;
        bn = rem % nbn;
    } else {
        bm = blockIdx.x / nbn; bn = blockIdx.x % nbn; sk = 0;
    }
    const int brow = bm << 8;
    const int bcol = bn << 8;
    const int Ksub = K / SK;
    const int koff = sk * Ksub;
    const int NKT = Ksub >> 6;       // even
    const int NI = NKT >> 1;
    float* __restrict__ C = (SK == 2 && sk == 1) ? C1 : C0;

    const int srow = tid >> 3;
    const int scol = ((tid & 7) << 3) ^ ((srow & 7) << 3);

    auto stA = [&](int kt, int h) {
        const unsigned short* s = A + (size_t)(brow + h * 128 + srow) * K + koff + kt * 64 + scol;
        unsigned short* d = &ldsA[kt % 3][h][tid * 8];
        GLL(s, d);
        GLL(s + (size_t)64 * K, d + 4096);
    };
    auto stB = [&](int kt, int h) {
        const unsigned short* s = B + (size_t)(bcol + h * 128 + srow) * K + koff + kt * 64 + scol;
        unsigned short* d = &ldsB[kt & 1][h][tid * 8];
        GLL(s, d);
        GLL(s + (size_t)64 * K, d + 4096);
    };

    f32x4 acc[8][4] = {};
    bf16x8 breg[4][2];

    // prologue: tiles 0 and 1 fully staged; wait tile0 (8 oldest), tile1 in flight.
    stA(0, 0); stA(0, 1); stB(0, 0); stB(0, 1);
    stA(1, 0); stA(1, 1); stB(1, 0); stB(1, 1);
    VMW(8);
    BAR();

    for (int it = 0; it < NI; ++it) {
        const int kt0 = 2 * it;
        const int ktA = kt0 + 2, ktB = kt0 + 3;
        const bool pf = ktA < NKT;     // even NKT => ktA<NKT iff ktB<NKT
        const int s0 = kt0 % 3;
        const int s1 = (kt0 + 1) % 3;

        // ---- phase 1 (tile kt0, q0; load B regs for dbuf0) ----
        {
            bf16x8 a00 = LDA8(s0, 0, 0, 0), a10 = LDA8(s0, 0, 1, 0);
            bf16x8 a01 = LDA8(s0, 0, 0, 1), a11 = LDA8(s0, 0, 1, 1);
#pragma unroll
            for (int j = 0; j < 4; ++j) { breg[j][0] = LDB8(0, j, 0); breg[j][1] = LDB8(0, j, 1); }
            if (pf) stA(ktA, 0);
            BAR(); LGKM0();
            MFMA16(0, a00, a10, a01, a11);
            BAR();
        }
        // ---- phase 2 ----
        {
            bf16x8 a00 = LDA8(s0, 1, 0, 0), a10 = LDA8(s0, 1, 1, 0);
            bf16x8 a01 = LDA8(s0, 1, 0, 1), a11 = LDA8(s0, 1, 1, 1);
            if (pf) { stA(ktA, 1); stB(ktA, 0); }
            BAR(); LGKM0();
            MFMA16(1, a00, a10, a01, a11);
            BAR();
        }
        // ---- phase 3 ----
        {
            bf16x8 a00 = LDA8(s0, 2, 0, 0), a10 = LDA8(s0, 2, 1, 0);
            bf16x8 a01 = LDA8(s0, 2, 0, 1), a11 = LDA8(s0, 2, 1, 1);
            if (pf) stB(ktA, 1);
            BAR(); LGKM0();
            MFMA16(2, a00, a10, a01, a11);
            BAR();
        }
        // ---- phase 4 + wait for tile kt0+1 ----
        {
            bf16x8 a00 = LDA8(s0, 3, 0, 0), a10 = LDA8(s0, 3, 1, 0);
            bf16x8 a01 = LDA8(s0, 3, 0, 1), a11 = LDA8(s0, 3, 1, 1);
            BAR(); LGKM0();
            MFMA16(3, a00, a10, a01, a11);
            if (pf) { VMW(8); } else { VMW(0); }
            BAR();
        }
        // ---- phase 5 (tile kt0+1, q0; load B regs for dbuf1) ----
        {
            bf16x8 a00 = LDA8(s1, 0, 0, 0), a10 = LDA8(s1, 0, 1, 0);
            bf16x8 a01 = LDA8(s1, 0, 0, 1), a11 = LDA8(s1, 0, 1, 1);
#pragma unroll
            for (int j = 0; j < 4; ++j) { breg[j][0] = LDB8(1, j, 0); breg[j][1] = LDB8(1, j, 1); }
            if (pf) stA(ktB, 0);
            BAR(); LGKM0();
            MFMA16(0, a00, a10, a01, a11);
            BAR();
        }
        // ---- phase 6 ----
        {
            bf16x8 a00 = LDA8(s1, 1, 0, 0), a10 = LDA8(s1, 1, 1, 0);
            bf16x8 a01 = LDA8(s1, 1, 0, 1), a11 = LDA8(s1, 1, 1, 1);
            if (pf) { stA(ktB, 1); stB(ktB, 0); }
            BAR(); LGKM0();
            MFMA16(1, a00, a10, a01, a11);
            BAR();
        }
        // ---- phase 7 ----
        {
            bf16x8 a00 = LDA8(s1, 2, 0, 0), a10 = LDA8(s1, 2, 1, 0);
            bf16x8 a01 = LDA8(s1, 2, 0, 1), a11 = LDA8(s1, 2, 1, 1);
            if (pf) stB(ktB, 1);
            BAR(); LGKM0();
            MFMA16(2, a00, a10, a01, a11);
            BAR();
        }
        // ---- phase 8 + wait for tile kt0+2 ----
        {
            bf16x8 a00 = LDA8(s1, 3, 0, 0), a10 = LDA8(s1, 3, 1, 0);
            bf16x8 a01 = LDA8(s1, 3, 0, 1), a11 = LDA8(s1, 3, 1, 1);
            BAR(); LGKM0();
            MFMA16(3, a00, a10, a01, a11);
            if (pf) VMW(8);
            BAR();
        }
    }

    // ---- epilogues ----
    if constexpr (EPI == 2) {
        // bf16 logits + per-(row, 64-col) softmax stats
        const int nblk = N >> 6;
        const int cblk = (bcol >> 6) + wn;
#pragma unroll
        for (int i = 0; i < 8; ++i) {
#pragma unroll
            for (int r = 0; r < 4; ++r) {
                float v0 = acc[i][0][r] * scale, v1 = acc[i][1][r] * scale;
                float v2 = acc[i][2][r] * scale, v3 = acc[i][3][r] * scale;
                float mv = fmaxf(fmaxf(v0, v1), fmaxf(v2, v3));
#pragma unroll
                for (int mk = 1; mk < 16; mk <<= 1) mv = fmaxf(mv, __shfl_xor(mv, mk));
                float sv = __expf(v0 - mv) + __expf(v1 - mv) + __expf(v2 - mv) + __expf(v3 - mv);
#pragma unroll
                for (int mk = 1; mk < 16; mk <<= 1) sv += __shfl_xor(sv, mk);
                int row = brow + wm * 128 + i * 16 + (g << 2) + r;
                if (fm == 0) {
                    pS[(size_t)row * nblk + cblk] = mv;
                    pQ[(size_t)row * nblk + cblk] = sv;
                }
                Cb[(size_t)row * N + bcol + wn * 64 + 0 * 16 + fm] = f2bf(v0);
                Cb[(size_t)row * N + bcol + wn * 64 + 1 * 16 + fm] = f2bf(v1);
                Cb[(size_t)row * N + bcol + wn * 64 + 2 * 16 + fm] = f2bf(v2);
                Cb[(size_t)row * N + bcol + wn * 64 + 3 * 16 + fm] = f2bf(v3);
            }
        }
    } else if constexpr (EPI == 3) {
        // bf16 z + bias + LN partial sums
        const int nblk = N >> 6;
        const int cblk = (bcol >> 6) + wn;
        float bj[4];
#pragma unroll
        for (int j = 0; j < 4; ++j) bj[j] = bias[bcol + wn * 64 + j * 16 + fm];
#pragma unroll
        for (int i = 0; i < 8; ++i) {
#pragma unroll
            for (int r = 0; r < 4; ++r) {
                float z[4];
#pragma unroll
                for (int j = 0; j < 4; ++j) z[j] = acc[i][j][r] * scale + bj[j];
                float s = z[0] + z[1] + z[2] + z[3];
                float q = z[0] * z[0] + z[1] * z[1] + z[2] * z[2] + z[3] * z[3];
#pragma unroll
                for (int mk = 1; mk < 16; mk <<= 1) { s += __shfl_xor(s, mk); q += __shfl_xor(q, mk); }
                int row = brow + wm * 128 + i * 16 + (g << 2) + r;
                if (fm == 0) {
                    pS[(size_t)row * nblk + cblk] = s;
                    pQ[(size_t)row * nblk + cblk] = q;
                }
#pragma unroll
                for (int j = 0; j < 4; ++j)
                    Cb[(size_t)row * N + bcol + wn * 64 + j * 16 + fm] = f2bf(z[j]);
            }
        }
    } else {
#pragma unroll
        for (int i = 0; i < 8; ++i) {
#pragma unroll
            for (int j = 0; j < 4; ++j) {
                int col = bcol + wn * 64 + j * 16 + fm;
                float badd = bias ? bias[col] : 0.0f;
#pragma unroll
                for (int r = 0; r < 4; ++r) {
                    int row = brow + wm * 128 + i * 16 + (g << 2) + r;
                    C[(size_t)row * N + col] = acc[i][j][r] * scale + badd;
                }
            }
        }
    }
}

// ============ pipelined bf16 GEMM (old structure, kept for o-GEMM) ============
template<int BN, int WM, int WN, int NSLOT>
__global__ __launch_bounds__(512) void k_gemm_big(const unsigned short* __restrict__ A,
                                                  const unsigned short* __restrict__ B,
                                                  float* __restrict__ C,
                                                  int M, int N, int K,
                                                  float scale,
                                                  const float* __restrict__ bias) {
    constexpr int MREP = 256 / WM / 16;
    constexpr int NREP = BN / WN / 16;
    constexpr int PHASES = MREP / 4;
    constexpr int BISS = BN / 128;
    constexpr int TISS = 2 + BISS;
    constexpr int DEPTH = NSLOT - 1;
    constexpr int ASLOT = 256 * 32;
    constexpr int BSLOT = BN * 32;
    constexpr int SLOT = ASLOT + BSLOT;
    __shared__ unsigned short lds[NSLOT * SLOT];

    const int tid = threadIdx.x;
    const int lane = tid & 63;
    const int wid = tid >> 6;
    const int wm = wid / WN;
    const int wn = wid % WN;
    const int fm = lane & 15;
    const int g = lane >> 4;

    const int nbn = N / BN;
    int bm, bn;
    if ((gridDim.x & 7) == 0) {
        int wg = (blockIdx.x & 7) * (gridDim.x >> 3) + (blockIdx.x >> 3);
        bm = wg / nbn; bn = wg % nbn;
    } else {
        bm = blockIdx.x / nbn; bn = blockIdx.x % nbn;
    }
    const int brow = bm << 8;
    const int bcol = bn * BN;
    const int NT = K >> 5;

    const int arow = tid >> 2;
    const int scb = ((tid & 3) << 4) ^ ((arow & 6) << 3);
    const unsigned short* gA = A + (size_t)(brow + arow) * K + (scb >> 1);
    const unsigned short* gB = B + (size_t)(bcol + arow) * K + (scb >> 1);
    unsigned short* lA = lds + tid * 8;
    unsigned short* lB = lds + ASLOT + tid * 8;
    const size_t rows128 = (size_t)128 * K;

    auto stageA = [&](int kt, int slot) {
        const unsigned short* s = gA + ((size_t)kt << 5);
        unsigned short* d = lA + slot * SLOT;
        GLL(s, d);
        GLL(s + rows128, d + 4096);
    };
    auto stageB = [&](int kt, int slot) {
        const unsigned short* s = gB + ((size_t)kt << 5);
        unsigned short* d = lB + slot * SLOT;
#pragma unroll
        for (int h = 0; h < BISS; ++h)
            GLL(s + (size_t)h * rows128, d + h * 4096);
    };

    const int cbf = (((g << 4) ^ ((fm & 6) << 3)) >> 1);
    const unsigned short* fA = lds + (wm * (256 / WM) + fm) * 32 + cbf;
    const unsigned short* fB = lds + ASLOT + (wn * (BN / WN) + fm) * 32 + cbf;

    f32x4 acc[MREP][NREP] = {};

#pragma unroll
    for (int p = 0; p < DEPTH; ++p) { stageA(p, p); stageB(p, p); }
    asm volatile("s_waitcnt vmcnt(%0)" :: "n"((DEPTH - 1) * TISS) : "memory");
    __builtin_amdgcn_s_barrier();

    for (int t = 0; t < NT; ++t) {
        const int slot = t % NSLOT;
        const unsigned short* sA = fA + slot * SLOT;
        const unsigned short* sB = fB + slot * SLOT;
        const int pslot = (t + DEPTH) % NSLOT;
        const bool pf = (t + DEPTH) < NT;

        bf16x8 bfr[NREP];
        bf16x8 afr[4];
#pragma unroll
        for (int i = 0; i < 4; ++i) afr[i] = *(const bf16x8*)(sA + i * 512);
#pragma unroll
        for (int j = 0; j < NREP; ++j) bfr[j] = *(const bf16x8*)(sB + j * 512);
        if (pf) {
            stageA(t + DEPTH, pslot);
            if (PHASES == 1) stageB(t + DEPTH, pslot);
        }
        __builtin_amdgcn_s_barrier();
        asm volatile("s_waitcnt lgkmcnt(0)" ::: "memory");
        __builtin_amdgcn_s_setprio(1);
#pragma unroll
        for (int i = 0; i < 4; ++i)
#pragma unroll
            for (int j = 0; j < NREP; ++j)
                acc[i][j] = __builtin_amdgcn_mfma_f32_16x16x32_bf16(afr[i], bfr[j], acc[i][j], 0, 0, 0);
        __builtin_amdgcn_s_setprio(0);
        __builtin_amdgcn_s_barrier();

        if (PHASES == 2) {
#pragma unroll
            for (int i = 0; i < 4; ++i) afr[i] = *(const bf16x8*)(sA + (i + 4) * 512);
            if (pf) stageB(t + DEPTH, pslot);
            __builtin_amdgcn_s_barrier();
            asm volatile("s_waitcnt lgkmcnt(0)" ::: "memory");
            __builtin_amdgcn_s_setprio(1);
#pragma unroll
            for (int i = 0; i < 4; ++i)
#pragma unroll
                for (int j = 0; j < NREP; ++j)
                    acc[(i + 4) % MREP][j] = __builtin_amdgcn_mfma_f32_16x16x32_bf16(afr[i], bfr[j], acc[(i + 4) % MREP][j], 0, 0, 0);
            __builtin_amdgcn_s_setprio(0);
        }

        if (t + 1 < NT) {
            if (t + DEPTH < NT)
                asm volatile("s_waitcnt vmcnt(%0)" :: "n"(TISS) : "memory");
            else
                asm volatile("s_waitcnt vmcnt(0)" ::: "memory");
        }
        __builtin_amdgcn_s_barrier();
    }

    const int r0 = g << 2;
#pragma unroll
    for (int i = 0; i < MREP; ++i)
#pragma unroll
        for (int j = 0; j < NREP; ++j) {
            int col = bcol + wn * (BN / WN) + j * 16 + fm;
            float badd = bias ? bias[col] : 0.0f;
#pragma unroll
            for (int r = 0; r < 4; ++r) {
                int row = brow + wm * (256 / WM) + i * 16 + r0 + r;
                C[(size_t)row * N + col] = acc[i][j][r] * scale + badd;
            }
        }
}

extern "C" void kernel_launch(void* const* d_in, const int* in_sizes, int n_in,
                              void* d_out, int out_size, void* d_ws, size_t ws_size,
                              hipStream_t stream) {
    const float* x     = (const float*)d_in[0];
    const float* Wq    = (const float*)d_in[1];
    const float* bq    = (const float*)d_in[2];
    const float* gq    = (const float*)d_in[3];
    const float* betaq = (const float*)d_in[4];
    const float* Wk    = (const float*)d_in[5];
    const float* bk    = (const float*)d_in[6];
    const float* gk    = (const float*)d_in[7];
    const float* betak = (const float*)d_in[8];
    const float* Wv    = (const float*)d_in[9];
    const float* bv    = (const float*)d_in[10];
    const float* gv    = (const float*)d_in[11];
    const float* betav = (const float*)d_in[12];
    const float* Wo    = (const float*)d_in[13];
    const float* bo    = (const float*)d_in[14];
    const float* Wc    = (const float*)d_in[15];
    const float* bc    = (const float*)d_in[16];

    float* out_o    = (float*)d_out;
    float* out_c    = out_o + (size_t)S_SEQ * D_DIM;
    float* out_attn = out_c + (size_t)S_SEQ * NCLS;

    char* cur = (char*)d_ws;
    auto alloc = [&](size_t bytes) {
        char* p = cur;
        cur += (bytes + 255) & ~(size_t)255;
        return p;
    };
    const size_t SD2 = (size_t)S_SEQ * D_DIM * 2;
    const size_t DD2 = (size_t)D_DIM * D_DIM * 2;
    unsigned short* xb   = (unsigned short*)alloc(SD2);
    unsigned short* wqkv = (unsigned short*)alloc(3 * DD2);
    unsigned short* wto  = (unsigned short*)alloc(DD2);
    unsigned short* qb   = (unsigned short*)alloc(SD2);
    unsigned short* kb   = (unsigned short*)alloc(SD2);
    unsigned short* Vt   = (unsigned short*)alloc(SD2);
    unsigned short* valb = (unsigned short*)alloc(SD2);
    float* rmax   = (float*)alloc((size_t)S_SEQ * 4);
    float* rrecip = (float*)alloc((size_t)S_SEQ * 4);
    float* bqkv   = (float*)alloc((size_t)3 * D_DIM * 4);
    float* vstat  = (float*)alloc((size_t)S_SEQ * 2 * 4);
    float* pS     = (float*)alloc((size_t)S_SEQ * 48 * 4);
    float* pQ     = (float*)alloc((size_t)S_SEQ * 48 * 4);
    unsigned short* At = (unsigned short*)alloc((size_t)S_SEQ * S_SEQ * 2);
    unsigned short* Lb = (unsigned short*)alloc((size_t)S_SEQ * S_SEQ * 2);

    // overlays: QK^T softmax partial stats over xb (dead after QKV GEMM);
    // split-K partial over qb+kb (dead after QK^T; 32 MB exactly).
    float* pmax = (float*)xb;
    float* psum = pmax + (size_t)S_SEQ * 128;
    float* part1 = (float*)qb;
    // QKV bf16 z lives in the (not-yet-written) attention output region.
    unsigned short* zb = (unsigned short*)out_attn;

    const int n4_xd = S_SEQ * D_DIM / 4;

    // x -> bf16
    k_f32_to_bf16<<<n4_xd / 256, 256, 0, stream>>>(x, xb, n4_xd);
    // all 4 weight transposes in one launch
    k_transpose4<<<dim3(16, 16, 4), 256, 0, stream>>>(Wq, Wk, Wv, Wo, wqkv, wto);
    k_concat3<<<12, 256, 0, stream>>>(bq, bk, bv, bqkv);
    // classifier (independent)
    k_classifier<<<S_SEQ, 256, 0, stream>>>(x, Wc, bc, out_c);

    // fused QKV GEMM (deep 8-phase, EPI=3): bf16 z + bias + LN partial sums
    k_gemm_8ph<1, 3, 0><<<(S_SEQ / 256) * (3 * D_DIM / 256), 512, 0, stream>>>(
        xb, wqkv, nullptr, nullptr, zb, S_SEQ, 3 * D_DIM, D_DIM, 1.0f, bqkv, pS, pQ);
    // LN apply q/k + V-stats
    k_ln_apply_qk<<<S_SEQ, 256, 0, stream>>>(zb, pS, pQ, gq, betaq, gk, betak, qb, kb, vstat);
    // LN-V + transpose directly from zb -> Vt
    k_transpose_lnv<<<dim3(S_SEQ / 64, D_DIM / 64), 256, 0, stream>>>(zb, vstat, gv, betav, Vt);

    // logits = q k^T / 32 -> bf16 Lb (deep 8-phase, npx mapping), fused softmax stats
    k_gemm_8ph<1, 2, 1><<<(S_SEQ / 256) * (S_SEQ / 256), 512, 0, stream>>>(
        qb, kb, nullptr, nullptr, Lb, S_SEQ, S_SEQ, D_DIM, 0.03125f, nullptr, pmax, psum);

    // combine stats, then normalize -> fp32 attention output + bf16 At
    k_stats_reduce<<<S_SEQ / 4, 256, 0, stream>>>(pmax, psum, rmax, rrecip, S_SEQ / 64);
    k_norm_transpose<<<dim3(S_SEQ / 64, S_SEQ / 64), 256, 0, stream>>>(
        Lb, out_attn, rmax, rrecip, At);

    // values = A^T V (deep 8-phase, split-K=2), sum -> bf16
    k_gemm_8ph<2, 0, 0><<<2 * (S_SEQ / 256) * (D_DIM / 256), 512, 0, stream>>>(
        At, Vt, out_o, part1, nullptr, S_SEQ, D_DIM, S_SEQ, 1.0f, nullptr, nullptr, nullptr);
    k_sum2_bf16<<<n4_xd / 256, 256, 0, stream>>>(out_o, part1, valb, n4_xd);

    // o = values @ Wo + bo (old structure)
    k_gemm_big<128, 4, 2, 3><<<(S_SEQ / 256) * (D_DIM / 128), 512, 0, stream>>>(
        valb, wto, out_o, S_SEQ, D_DIM, D_DIM, 1.0f, bo);
}

// Round 11
// 557.929 us; speedup vs baseline: 1.1576x; 1.1576x over previous
//
#include <hip/hip_runtime.h>
#include <hip/hip_bf16.h>

#define S_SEQ 8192
#define D_DIM 1024
#define NCLS 7

typedef __bf16 bf16x8 __attribute__((ext_vector_type(8)));
typedef float f32x4 __attribute__((ext_vector_type(4)));

typedef const __attribute__((address_space(1))) void* gas_ptr;
typedef __attribute__((address_space(3))) void* las_ptr;
#define GLL(gp, lp) __builtin_amdgcn_global_load_lds((gas_ptr)(const void*)(gp), (las_ptr)(void*)(lp), 16, 0, 0)

__device__ __forceinline__ unsigned short f2bf(float f) {
    unsigned int u = __builtin_bit_cast(unsigned int, f);
    u = (u + 0x7FFFu + ((u >> 16) & 1u)) >> 16;
    return (unsigned short)u;
}
__device__ __forceinline__ float bf2f(unsigned short h) {
    unsigned int u = ((unsigned int)h) << 16;
    return __builtin_bit_cast(float, u);
}

// ---------------- sum of two fp32 arrays -> bf16 ----------------
__global__ __launch_bounds__(256) void k_sum2_bf16(const float* __restrict__ a,
                                                   const float* __restrict__ b,
                                                   unsigned short* __restrict__ dst, int n4) {
    int i = blockIdx.x * 256 + threadIdx.x;
    if (i >= n4) return;
    float4 va = ((const float4*)a)[i];
    float4 vb = ((const float4*)b)[i];
    ushort4 o;
    o.x = f2bf(va.x + vb.x); o.y = f2bf(va.y + vb.y);
    o.z = f2bf(va.z + vb.z); o.w = f2bf(va.w + vb.w);
    ((ushort4*)dst)[i] = o;
}

// ---------------- concat 3 bias vectors [1024] -> [3072] ----------------
__global__ __launch_bounds__(256) void k_concat3(const float* __restrict__ a,
                                                 const float* __restrict__ b,
                                                 const float* __restrict__ c,
                                                 float* __restrict__ out) {
    int i = blockIdx.x * 256 + threadIdx.x;
    float v = (i < 1024) ? a[i] : (i < 2048) ? b[i - 1024] : c[i - 2048];
    out[i] = v;
}

// ------- fused transpose of 4 weight matrices: fp32 [K][N] -> bf16 [N][K] -------
__global__ __launch_bounds__(256) void k_transpose4(const float* __restrict__ W0,
                                                    const float* __restrict__ W1,
                                                    const float* __restrict__ W2,
                                                    const float* __restrict__ W3,
                                                    unsigned short* __restrict__ dqkv,
                                                    unsigned short* __restrict__ dsto) {
    __shared__ unsigned short t[64][80];
    const float* srcs[4] = {W0, W1, W2, W3};
    const int z = blockIdx.z;
    const float* src = srcs[z];
    unsigned short* dst = (z < 3) ? (dqkv + (size_t)z * D_DIM * D_DIM) : dsto;
    const int C = D_DIM, R = D_DIM;
    int r0 = blockIdx.x * 64, c0 = blockIdx.y * 64;
    int tid = threadIdx.x;
    int rr = tid >> 4, cc = (tid & 15) << 2;
#pragma unroll
    for (int p = 0; p < 4; ++p) {
        int r = rr + p * 16;
        float4 v = *(const float4*)(src + (size_t)(r0 + r) * C + c0 + cc);
        t[cc + 0][r] = f2bf(v.x);
        t[cc + 1][r] = f2bf(v.y);
        t[cc + 2][r] = f2bf(v.z);
        t[cc + 3][r] = f2bf(v.w);
    }
    __syncthreads();
    int wr = tid >> 3, wc = (tid & 7) << 3;
#pragma unroll
    for (int p = 0; p < 2; ++p) {
        int c = wr + p * 32;
        uint4 v8 = *(const uint4*)&t[c][wc];
        *(uint4*)(dst + (size_t)(c0 + c) * R + r0 + wc) = v8;
    }
}

// ---- fused x->bf16 cast + classifier: reads x once per row ----
__global__ __launch_bounds__(256) void k_cast_classify(const float* __restrict__ x,
                                                       const float* __restrict__ Wc,
                                                       const float* __restrict__ bc,
                                                       unsigned short* __restrict__ xb,
                                                       float* __restrict__ outc) {
    __shared__ float red[4][NCLS];
    int row = blockIdx.x, tid = threadIdx.x;
    size_t off = (size_t)row * D_DIM + tid * 4;
    float4 xv = *(const float4*)(x + off);
    ushort4 o4;
    o4.x = f2bf(xv.x); o4.y = f2bf(xv.y); o4.z = f2bf(xv.z); o4.w = f2bf(xv.w);
    *(ushort4*)(xb + off) = o4;
    const float* w0 = Wc + (size_t)(tid * 4) * NCLS;
    float acc[NCLS];
#pragma unroll
    for (int j = 0; j < NCLS; ++j)
        acc[j] = xv.x * w0[j] + xv.y * w0[NCLS + j] + xv.z * w0[2 * NCLS + j] + xv.w * w0[3 * NCLS + j];
#pragma unroll
    for (int j = 0; j < NCLS; ++j)
#pragma unroll
        for (int o = 32; o; o >>= 1) acc[j] += __shfl_down(acc[j], o);
    int lane = tid & 63, wv = tid >> 6;
    if (lane == 0) {
#pragma unroll
        for (int j = 0; j < NCLS; ++j) red[wv][j] = acc[j];
    }
    __syncthreads();
    if (tid < NCLS) {
        float s = red[0][tid] + red[1][tid] + red[2][tid] + red[3][tid];
        outc[(size_t)row * NCLS + tid] = s + bc[tid];
    }
}

// ---- LN apply (q,k) + V-stat store ----
__global__ __launch_bounds__(256) void k_ln_apply_qk(const unsigned short* __restrict__ zb,
                                                     const float* __restrict__ pS,
                                                     const float* __restrict__ pQ,
                                                     const float* __restrict__ gq, const float* __restrict__ betaq,
                                                     const float* __restrict__ gk, const float* __restrict__ betak,
                                                     unsigned short* __restrict__ qb,
                                                     unsigned short* __restrict__ kb,
                                                     float* __restrict__ vstat) {
    __shared__ float sS[48], sQ[48];
    int row = blockIdx.x, tid = threadIdx.x;
    if (tid < 48) { sS[tid] = pS[(size_t)row * 48 + tid]; sQ[tid] = pQ[(size_t)row * 48 + tid]; }
    __syncthreads();
    float m[3], rs[3];
#pragma unroll
    for (int c = 0; c < 3; ++c) {
        float s = 0.0f, q = 0.0f;
#pragma unroll
        for (int j = 0; j < 16; ++j) { s += sS[c * 16 + j]; q += sQ[c * 16 + j]; }
        float mm = s * (1.0f / D_DIM);
        float var = q * (1.0f / D_DIM) - mm * mm;
        m[c] = mm; rs[c] = rsqrtf(var + 1e-5f);
    }
    if (tid == 0) { vstat[2 * row] = m[2]; vstat[2 * row + 1] = rs[2]; }
    const unsigned short* zrow = zb + (size_t)row * 3072;
    {
        ushort4 u = *(const ushort4*)(zrow + tid * 4);
        float4 g4 = *(const float4*)(gq + tid * 4);
        float4 b4 = *(const float4*)(betaq + tid * 4);
        ushort4 o;
        o.x = f2bf((bf2f(u.x) - m[0]) * rs[0] * g4.x + b4.x);
        o.y = f2bf((bf2f(u.y) - m[0]) * rs[0] * g4.y + b4.y);
        o.z = f2bf((bf2f(u.z) - m[0]) * rs[0] * g4.z + b4.z);
        o.w = f2bf((bf2f(u.w) - m[0]) * rs[0] * g4.w + b4.w);
        *(ushort4*)(qb + (size_t)row * D_DIM + tid * 4) = o;
    }
    {
        ushort4 u = *(const ushort4*)(zrow + 1024 + tid * 4);
        float4 g4 = *(const float4*)(gk + tid * 4);
        float4 b4 = *(const float4*)(betak + tid * 4);
        ushort4 o;
        o.x = f2bf((bf2f(u.x) - m[1]) * rs[1] * g4.x + b4.x);
        o.y = f2bf((bf2f(u.y) - m[1]) * rs[1] * g4.y + b4.y);
        o.z = f2bf((bf2f(u.z) - m[1]) * rs[1] * g4.z + b4.z);
        o.w = f2bf((bf2f(u.w) - m[1]) * rs[1] * g4.w + b4.w);
        *(ushort4*)(kb + (size_t)row * D_DIM + tid * 4) = o;
    }
}

// ---- LN-V + transpose: zb V-slice -> Vt ----
__global__ __launch_bounds__(256) void k_transpose_lnv(const unsigned short* __restrict__ zb,
                                                       const float* __restrict__ vstat,
                                                       const float* __restrict__ gv,
                                                       const float* __restrict__ betav,
                                                       unsigned short* __restrict__ Vt) {
    __shared__ unsigned short t[64][80];
    int s0 = blockIdx.x * 64, d0 = blockIdx.y * 64;
    int tid = threadIdx.x;
    int rr = tid >> 3, cc = (tid & 7) << 3;
    float4 g0 = *(const float4*)(gv + d0 + cc);
    float4 g1 = *(const float4*)(gv + d0 + cc + 4);
    float4 b0 = *(const float4*)(betav + d0 + cc);
    float4 b1 = *(const float4*)(betav + d0 + cc + 4);
    float gg[8] = {g0.x, g0.y, g0.z, g0.w, g1.x, g1.y, g1.z, g1.w};
    float bb[8] = {b0.x, b0.y, b0.z, b0.w, b1.x, b1.y, b1.z, b1.w};
#pragma unroll
    for (int p = 0; p < 2; ++p) {
        int r = rr + p * 32;
        float m = vstat[2 * (s0 + r)], rs = vstat[2 * (s0 + r) + 1];
        uint4 u = *(const uint4*)(zb + (size_t)(s0 + r) * 3072 + 2048 + d0 + cc);
        const unsigned short* pu = (const unsigned short*)&u;
#pragma unroll
        for (int i = 0; i < 8; ++i)
            t[cc + i][r] = f2bf((bf2f(pu[i]) - m) * rs * gg[i] + bb[i]);
    }
    __syncthreads();
    int wr = tid >> 3, wc = (tid & 7) << 3;
#pragma unroll
    for (int p = 0; p < 2; ++p) {
        int c = wr + p * 32;
        uint4 v8 = *(const uint4*)&t[c][wc];
        *(uint4*)(Vt + (size_t)(d0 + c) * S_SEQ + s0 + wc) = v8;
    }
}

// ---------------- combine per-tile stats ----------------
__global__ __launch_bounds__(256) void k_stats_reduce(const float* __restrict__ pmax,
                                                      const float* __restrict__ psum,
                                                      float* __restrict__ rmax,
                                                      float* __restrict__ rrecip, int nblk) {
    int row = blockIdx.x * 4 + (threadIdx.x >> 6);
    int lane = threadIdx.x & 63;
    const float* pm = pmax + (size_t)row * nblk;
    const float* ps = psum + (size_t)row * nblk;
    float m = -3.4e38f;
    for (int j = lane; j < nblk; j += 64) m = fmaxf(m, pm[j]);
#pragma unroll
    for (int mk = 32; mk; mk >>= 1) m = fmaxf(m, __shfl_xor(m, mk));
    float s = 0.0f;
    for (int j = lane; j < nblk; j += 64) s += ps[j] * __expf(pm[j] - m);
#pragma unroll
    for (int mk = 32; mk; mk >>= 1) s += __shfl_xor(s, mk);
    if (lane == 0) { rmax[row] = m; rrecip[row] = 1.0f / s; }
}

// ------- normalize: bf16 logits -> fp32 attn + bf16 At -------
__global__ __launch_bounds__(256) void k_norm_transpose(const unsigned short* __restrict__ src16,
                                                        float* __restrict__ attn,
                                                        const float* __restrict__ rmax,
                                                        const float* __restrict__ rrecip,
                                                        unsigned short* __restrict__ At) {
    __shared__ unsigned short t[64][80];
    int t0 = blockIdx.x * 64, s0 = blockIdx.y * 64;
    int tid = threadIdx.x;
    int rr = tid >> 3, cc = (tid & 7) << 3;
#pragma unroll
    for (int p = 0; p < 2; ++p) {
        int r = rr + p * 32;
        float m = rmax[t0 + r], rc = rrecip[t0 + r];
        size_t off = (size_t)(t0 + r) * S_SEQ + s0 + cc;
        uint4 u = *(const uint4*)(src16 + off);
        const unsigned short* pu = (const unsigned short*)&u;
        float v[8];
#pragma unroll
        for (int i = 0; i < 8; ++i) {
            v[i] = __expf(bf2f(pu[i]) - m) * rc;
            t[cc + i][r] = f2bf(v[i]);
        }
        float4 o0 = {v[0], v[1], v[2], v[3]};
        float4 o1 = {v[4], v[5], v[6], v[7]};
        *(float4*)(attn + off) = o0;
        *(float4*)(attn + off + 4) = o1;
    }
    __syncthreads();
    int wr = tid >> 3, wc = (tid & 7) << 3;
#pragma unroll
    for (int p = 0; p < 2; ++p) {
        int c = wr + p * 32;
        uint4 v8 = *(const uint4*)&t[c][wc];
        *(uint4*)(At + (size_t)(s0 + c) * S_SEQ + t0 + wc) = v8;
    }
}

// ======== shared pieces for 8-phase GEMM ========
#define BAR()  __builtin_amdgcn_s_barrier()
#define LGKM0() asm volatile("s_waitcnt lgkmcnt(0)" ::: "memory")
#define VMW(n) asm volatile("s_waitcnt vmcnt(%0)" :: "n"(n) : "memory")

#define LD_A8(db, q, ii, ks) \
    (*(const bf16x8*)&lds[db][0][wm][((q)*32 + (ii)*16 + fm) * 64 + ((((ks)*32 + g*8)) ^ ((((q)*32 + (ii)*16 + fm) & 7) << 3))])
#define LD_B8(db, j, ks) \
    (*(const bf16x8*)&lds[db][1][wn >> 1][((wn & 1)*64 + (j)*16 + fm) * 64 + ((((ks)*32 + g*8)) ^ (((((wn & 1)*64 + (j)*16 + fm)) & 7) << 3))])

#define MFMA16(q, a00, a10, a01, a11)                                                          \
    {                                                                                          \
        __builtin_amdgcn_s_setprio(1);                                                         \
        _Pragma("unroll")                                                                      \
        for (int j = 0; j < 4; ++j) {                                                          \
            acc[(q)*2 + 0][j] = __builtin_amdgcn_mfma_f32_16x16x32_bf16(a00, breg[j][0], acc[(q)*2 + 0][j], 0, 0, 0); \
            acc[(q)*2 + 1][j] = __builtin_amdgcn_mfma_f32_16x16x32_bf16(a10, breg[j][0], acc[(q)*2 + 1][j], 0, 0, 0); \
            acc[(q)*2 + 0][j] = __builtin_amdgcn_mfma_f32_16x16x32_bf16(a01, breg[j][1], acc[(q)*2 + 0][j], 0, 0, 0); \
            acc[(q)*2 + 1][j] = __builtin_amdgcn_mfma_f32_16x16x32_bf16(a11, breg[j][1], acc[(q)*2 + 1][j], 0, 0, 0); \
        }                                                                                      \
        __builtin_amdgcn_s_setprio(0);                                                         \
    }

// ======== 8-phase 256x256 GEMM (non-persistent). EPI: 0=fp32+bias, 3=bf16+bias+LN-stats ========
template<int SK, int EPI>
__global__ __launch_bounds__(512) void k_gemm_8ph(const unsigned short* __restrict__ A,
                                                  const unsigned short* __restrict__ B,
                                                  float* __restrict__ C0,
                                                  float* __restrict__ C1,
                                                  unsigned short* __restrict__ Cb,
                                                  int M, int N, int K, float scale,
                                                  const float* __restrict__ bias,
                                                  float* __restrict__ pS,
                                                  float* __restrict__ pQ) {
    __shared__ unsigned short lds[2][2][2][8192];

    const int tid = threadIdx.x;
    const int lane = tid & 63;
    const int wid = tid >> 6;
    const int wm = wid >> 2;
    const int wn = wid & 3;
    const int fm = lane & 15;
    const int g = lane >> 4;

    const int nbm = M >> 8;
    const int nbn = N >> 8;
    int bm, bn, sk;
    if ((gridDim.x & 7) == 0) {
        int wg = (blockIdx.x & 7) * (gridDim.x >> 3) + (blockIdx.x >> 3);
        sk = wg / (nbm * nbn);
        int rem = wg % (nbm * nbn);
        bm = rem / nbn;
        bn = rem % nbn;
    } else {
        bm = blockIdx.x / nbn; bn = blockIdx.x % nbn; sk = 0;
    }
    const int brow = bm << 8;
    const int bcol = bn << 8;
    const int Ksub = K / SK;
    const int koff = sk * Ksub;
    const int NKT = Ksub >> 6;
    const int NI = NKT >> 1;
    float* __restrict__ C = (SK == 2 && sk == 1) ? C1 : C0;

    const int srow = tid >> 3;
    const int scol = ((tid & 7) << 3) ^ ((srow & 7) << 3);

    auto stA = [&](int kt, int h) {
        const unsigned short* s = A + (size_t)(brow + h * 128 + srow) * K + koff + kt * 64 + scol;
        unsigned short* d = &lds[kt & 1][0][h][tid * 8];
        GLL(s, d);
        GLL(s + (size_t)64 * K, d + 4096);
    };
    auto stB = [&](int kt, int h) {
        const unsigned short* s = B + (size_t)(bcol + h * 128 + srow) * K + koff + kt * 64 + scol;
        unsigned short* d = &lds[kt & 1][1][h][tid * 8];
        GLL(s, d);
        GLL(s + (size_t)64 * K, d + 4096);
    };

    f32x4 acc[8][4] = {};
    bf16x8 breg[4][2];

    stB(0, 0); stB(0, 1);
    stA(0, 0); stA(0, 1);
    stB(1, 0); stB(1, 1);
    VMW(4);
    BAR();

    for (int it = 0; it < NI; ++it) {
        const int kt1 = 2 * it + 1;
        const bool pfA = (2 * it + 2) < NKT;
        const bool pfB = (2 * it + 3) < NKT;

        {
            bf16x8 a00 = LD_A8(0, 0, 0, 0), a10 = LD_A8(0, 0, 1, 0);
            bf16x8 a01 = LD_A8(0, 0, 0, 1), a11 = LD_A8(0, 0, 1, 1);
#pragma unroll
            for (int j = 0; j < 4; ++j) { breg[j][0] = LD_B8(0, j, 0); breg[j][1] = LD_B8(0, j, 1); }
            stA(kt1, 0);
            BAR(); LGKM0();
            MFMA16(0, a00, a10, a01, a11);
            BAR();
        }
        {
            bf16x8 a00 = LD_A8(0, 1, 0, 0), a10 = LD_A8(0, 1, 1, 0);
            bf16x8 a01 = LD_A8(0, 1, 0, 1), a11 = LD_A8(0, 1, 1, 1);
            stA(kt1, 1);
            if (pfA) stB(2 * it + 2, 0);
            BAR(); LGKM0();
            MFMA16(1, a00, a10, a01, a11);
            BAR();
        }
        {
            bf16x8 a00 = LD_A8(0, 2, 0, 0), a10 = LD_A8(0, 2, 1, 0);
            bf16x8 a01 = LD_A8(0, 2, 0, 1), a11 = LD_A8(0, 2, 1, 1);
            if (pfA) stB(2 * it + 2, 1);
            BAR(); LGKM0();
            MFMA16(2, a00, a10, a01, a11);
            BAR();
        }
        {
            bf16x8 a00 = LD_A8(0, 3, 0, 0), a10 = LD_A8(0, 3, 1, 0);
            bf16x8 a01 = LD_A8(0, 3, 0, 1), a11 = LD_A8(0, 3, 1, 1);
            BAR(); LGKM0();
            MFMA16(3, a00, a10, a01, a11);
            if (pfA) { VMW(4); } else { VMW(0); }
            BAR();
        }
        {
            bf16x8 a00 = LD_A8(1, 0, 0, 0), a10 = LD_A8(1, 0, 1, 0);
            bf16x8 a01 = LD_A8(1, 0, 0, 1), a11 = LD_A8(1, 0, 1, 1);
#pragma unroll
            for (int j = 0; j < 4; ++j) { breg[j][0] = LD_B8(1, j, 0); breg[j][1] = LD_B8(1, j, 1); }
            if (pfA) stA(2 * it + 2, 0);
            BAR(); LGKM0();
            MFMA16(0, a00, a10, a01, a11);
            BAR();
        }
        {
            bf16x8 a00 = LD_A8(1, 1, 0, 0), a10 = LD_A8(1, 1, 1, 0);
            bf16x8 a01 = LD_A8(1, 1, 0, 1), a11 = LD_A8(1, 1, 1, 1);
            if (pfA) stA(2 * it + 2, 1);
            if (pfB) stB(2 * it + 3, 0);
            BAR(); LGKM0();
            MFMA16(1, a00, a10, a01, a11);
            BAR();
        }
        {
            bf16x8 a00 = LD_A8(1, 2, 0, 0), a10 = LD_A8(1, 2, 1, 0);
            bf16x8 a01 = LD_A8(1, 2, 0, 1), a11 = LD_A8(1, 2, 1, 1);
            if (pfB) stB(2 * it + 3, 1);
            BAR(); LGKM0();
            MFMA16(2, a00, a10, a01, a11);
            BAR();
        }
        {
            bf16x8 a00 = LD_A8(1, 3, 0, 0), a10 = LD_A8(1, 3, 1, 0);
            bf16x8 a01 = LD_A8(1, 3, 0, 1), a11 = LD_A8(1, 3, 1, 1);
            BAR(); LGKM0();
            MFMA16(3, a00, a10, a01, a11);
            if (it + 1 < NI) {
                if (pfB) { VMW(4); } else { VMW(0); }
            }
            BAR();
        }
    }

    if constexpr (EPI == 3) {
        const int nblk = N >> 6;
        const int cblk = (bcol >> 6) + wn;
        float bj[4];
#pragma unroll
        for (int j = 0; j < 4; ++j) bj[j] = bias[bcol + wn * 64 + j * 16 + fm];
#pragma unroll
        for (int i = 0; i < 8; ++i) {
#pragma unroll
            for (int r = 0; r < 4; ++r) {
                float z[4];
#pragma unroll
                for (int j = 0; j < 4; ++j) z[j] = acc[i][j][r] * scale + bj[j];
                float s = z[0] + z[1] + z[2] + z[3];
                float q = z[0] * z[0] + z[1] * z[1] + z[2] * z[2] + z[3] * z[3];
#pragma unroll
                for (int mk = 1; mk < 16; mk <<= 1) { s += __shfl_xor(s, mk); q += __shfl_xor(q, mk); }
                int row = brow + wm * 128 + i * 16 + (g << 2) + r;
                if (fm == 0) {
                    pS[(size_t)row * nblk + cblk] = s;
                    pQ[(size_t)row * nblk + cblk] = q;
                }
#pragma unroll
                for (int j = 0; j < 4; ++j)
                    Cb[(size_t)row * N + bcol + wn * 64 + j * 16 + fm] = f2bf(z[j]);
            }
        }
    } else {
#pragma unroll
        for (int i = 0; i < 8; ++i) {
#pragma unroll
            for (int j = 0; j < 4; ++j) {
                int col = bcol + wn * 64 + j * 16 + fm;
                float badd = bias ? bias[col] : 0.0f;
#pragma unroll
                for (int r = 0; r < 4; ++r) {
                    int row = brow + wm * 128 + i * 16 + (g << 2) + r;
                    C[(size_t)row * N + col] = acc[i][j][r] * scale + badd;
                }
            }
        }
    }
}

// ======== persistent QK^T: 4 bm-tiles per block at fixed bn, prologue/epilogue overlap ========
__global__ __launch_bounds__(512) void k_qkt_8ph(const unsigned short* __restrict__ A,
                                                 const unsigned short* __restrict__ B,
                                                 unsigned short* __restrict__ Cb,
                                                 float scale,
                                                 float* __restrict__ pmax,
                                                 float* __restrict__ psum) {
    __shared__ unsigned short lds[2][2][2][8192];
    const int K = D_DIM, N = S_SEQ;
    const int NKT = 16, NI = 8, REPS = 4;

    const int tid = threadIdx.x;
    const int lane = tid & 63;
    const int wid = tid >> 6;
    const int wm = wid >> 2;
    const int wn = wid & 3;
    const int fm = lane & 15;
    const int g = lane >> 4;

    const int xcd = blockIdx.x & 7;
    const int c = blockIdx.x >> 3;
    const int bn = xcd * 4 + (c & 3);
    const int bmbase = c >> 2;
    const int bcol = bn << 8;

    const int srow = tid >> 3;
    const int scol = ((tid & 7) << 3) ^ ((srow & 7) << 3);

    const unsigned short* gB = B + (size_t)(bcol + srow) * K + scol;
    auto gArep = [&](int rep) {
        return A + (size_t)(((bmbase + 8 * rep) << 8) + srow) * K + scol;
    };

    auto st = [&](const unsigned short* gb, int kt, int ab, int h) {
        const unsigned short* s = gb + (size_t)(h * 128) * K + kt * 64;
        unsigned short* d = &lds[kt & 1][ab][h][tid * 8];
        GLL(s, d);
        GLL(s + (size_t)64 * K, d + 4096);
    };

    f32x4 acc[8][4];
    bf16x8 breg[4][2];

    const unsigned short* gA0 = gArep(0);
    st(gB, 0, 1, 0); st(gB, 0, 1, 1);
    st(gA0, 0, 0, 0); st(gA0, 0, 0, 1);
    st(gB, 1, 1, 0); st(gB, 1, 1, 1);
    VMW(4);
    BAR();

    for (int rep = 0; rep < REPS; ++rep) {
        const unsigned short* gAc = gArep(rep);
        const unsigned short* gAn = gArep(rep + 1 < REPS ? rep + 1 : rep);
        const bool nrep = (rep + 1) < REPS;
        const int brow = (bmbase + 8 * rep) << 8;

#pragma unroll
        for (int i = 0; i < 8; ++i)
#pragma unroll
            for (int j = 0; j < 4; ++j) acc[i][j] = (f32x4){0.0f, 0.0f, 0.0f, 0.0f};

        for (int it = 0; it < NI; ++it) {
            const int kt1 = 2 * it + 1;
            const bool pfA = (2 * it + 2) < NKT;
            const bool pfB = (2 * it + 3) < NKT;

            {
                bf16x8 a00 = LD_A8(0, 0, 0, 0), a10 = LD_A8(0, 0, 1, 0);
                bf16x8 a01 = LD_A8(0, 0, 0, 1), a11 = LD_A8(0, 0, 1, 1);
#pragma unroll
                for (int j = 0; j < 4; ++j) { breg[j][0] = LD_B8(0, j, 0); breg[j][1] = LD_B8(0, j, 1); }
                st(gAc, kt1, 0, 0);
                BAR(); LGKM0();
                MFMA16(0, a00, a10, a01, a11);
                BAR();
            }
            {
                bf16x8 a00 = LD_A8(0, 1, 0, 0), a10 = LD_A8(0, 1, 1, 0);
                bf16x8 a01 = LD_A8(0, 1, 0, 1), a11 = LD_A8(0, 1, 1, 1);
                st(gAc, kt1, 0, 1);
                if (pfA) st(gB, 2 * it + 2, 1, 0);
                else if (nrep) st(gB, 0, 1, 0);
                BAR(); LGKM0();
                MFMA16(1, a00, a10, a01, a11);
                BAR();
            }
            {
                bf16x8 a00 = LD_A8(0, 2, 0, 0), a10 = LD_A8(0, 2, 1, 0);
                bf16x8 a01 = LD_A8(0, 2, 0, 1), a11 = LD_A8(0, 2, 1, 1);
                if (pfA) st(gB, 2 * it + 2, 1, 1);
                else if (nrep) st(gB, 0, 1, 1);
                BAR(); LGKM0();
                MFMA16(2, a00, a10, a01, a11);
                BAR();
            }
            {
                bf16x8 a00 = LD_A8(0, 3, 0, 0), a10 = LD_A8(0, 3, 1, 0);
                bf16x8 a01 = LD_A8(0, 3, 0, 1), a11 = LD_A8(0, 3, 1, 1);
                BAR(); LGKM0();
                MFMA16(3, a00, a10, a01, a11);
                if (pfA || nrep) { VMW(4); } else { VMW(0); }
                BAR();
            }
            {
                bf16x8 a00 = LD_A8(1, 0, 0, 0), a10 = LD_A8(1, 0, 1, 0);
                bf16x8 a01 = LD_A8(1, 0, 0, 1), a11 = LD_A8(1, 0, 1, 1);
#pragma unroll
                for (int j = 0; j < 4; ++j) { breg[j][0] = LD_B8(1, j, 0); breg[j][1] = LD_B8(1, j, 1); }
                if (pfA) st(gAc, 2 * it + 2, 0, 0);
                else if (nrep) st(gAn, 0, 0, 0);
                BAR(); LGKM0();
                MFMA16(0, a00, a10, a01, a11);
                BAR();
            }
            {
                bf16x8 a00 = LD_A8(1, 1, 0, 0), a10 = LD_A8(1, 1, 1, 0);
                bf16x8 a01 = LD_A8(1, 1, 0, 1), a11 = LD_A8(1, 1, 1, 1);
                if (pfA) st(gAc, 2 * it + 2, 0, 1);
                else if (nrep) st(gAn, 0, 0, 1);
                if (pfB) st(gB, 2 * it + 3, 1, 0);
                else if (nrep) st(gB, 1, 1, 0);
                BAR(); LGKM0();
                MFMA16(1, a00, a10, a01, a11);
                BAR();
            }
            {
                bf16x8 a00 = LD_A8(1, 2, 0, 0), a10 = LD_A8(1, 2, 1, 0);
                bf16x8 a01 = LD_A8(1, 2, 0, 1), a11 = LD_A8(1, 2, 1, 1);
                if (pfB) st(gB, 2 * it + 3, 1, 1);
                else if (nrep) st(gB, 1, 1, 1);
                BAR(); LGKM0();
                MFMA16(2, a00, a10, a01, a11);
                BAR();
            }
            {
                bf16x8 a00 = LD_A8(1, 3, 0, 0), a10 = LD_A8(1, 3, 1, 0);
                bf16x8 a01 = LD_A8(1, 3, 0, 1), a11 = LD_A8(1, 3, 1, 1);
                BAR(); LGKM0();
                MFMA16(3, a00, a10, a01, a11);
                if (it + 1 < NI) { VMW(4); }
                else if (nrep) { VMW(4); }
                BAR();
            }
        }

        {
            const int nblk = N >> 6;
            const int cblk = (bcol >> 6) + wn;
#pragma unroll
            for (int i = 0; i < 8; ++i) {
#pragma unroll
                for (int r = 0; r < 4; ++r) {
                    float v0 = acc[i][0][r] * scale, v1 = acc[i][1][r] * scale;
                    float v2 = acc[i][2][r] * scale, v3 = acc[i][3][r] * scale;
                    float mv = fmaxf(fmaxf(v0, v1), fmaxf(v2, v3));
#pragma unroll
                    for (int mk = 1; mk < 16; mk <<= 1) mv = fmaxf(mv, __shfl_xor(mv, mk));
                    float sv = __expf(v0 - mv) + __expf(v1 - mv) + __expf(v2 - mv) + __expf(v3 - mv);
#pragma unroll
                    for (int mk = 1; mk < 16; mk <<= 1) sv += __shfl_xor(sv, mk);
                    int row = brow + wm * 128 + i * 16 + (g << 2) + r;
                    if (fm == 0) {
                        pmax[(size_t)row * nblk + cblk] = mv;
                        psum[(size_t)row * nblk + cblk] = sv;
                    }
                    Cb[(size_t)row * N + bcol + wn * 64 + 0 * 16 + fm] = f2bf(v0);
                    Cb[(size_t)row * N + bcol + wn * 64 + 1 * 16 + fm] = f2bf(v1);
                    Cb[(size_t)row * N + bcol + wn * 64 + 2 * 16 + fm] = f2bf(v2);
                    Cb[(size_t)row * N + bcol + wn * 64 + 3 * 16 + fm] = f2bf(v3);
                }
            }
        }
    }
}

// ============ pipelined bf16 GEMM (old structure, kept for o-GEMM) ============
template<int BN, int WM, int WN, int NSLOT>
__global__ __launch_bounds__(512) void k_gemm_big(const unsigned short* __restrict__ A,
                                                  const unsigned short* __restrict__ B,
                                                  float* __restrict__ C,
                                                  int M, int N, int K,
                                                  float scale,
                                                  const float* __restrict__ bias) {
    constexpr int MREP = 256 / WM / 16;
    constexpr int NREP = BN / WN / 16;
    constexpr int PHASES = MREP / 4;
    constexpr int BISS = BN / 128;
    constexpr int TISS = 2 + BISS;
    constexpr int DEPTH = NSLOT - 1;
    constexpr int ASLOT = 256 * 32;
    constexpr int BSLOT = BN * 32;
    constexpr int SLOT = ASLOT + BSLOT;
    __shared__ unsigned short lds[NSLOT * SLOT];

    const int tid = threadIdx.x;
    const int lane = tid & 63;
    const int wid = tid >> 6;
    const int wm = wid / WN;
    const int wn = wid % WN;
    const int fm = lane & 15;
    const int g = lane >> 4;

    const int nbn = N / BN;
    int bm, bn;
    if ((gridDim.x & 7) == 0) {
        int wg = (blockIdx.x & 7) * (gridDim.x >> 3) + (blockIdx.x >> 3);
        bm = wg / nbn; bn = wg % nbn;
    } else {
        bm = blockIdx.x / nbn; bn = blockIdx.x % nbn;
    }
    const int brow = bm << 8;
    const int bcol = bn * BN;
    const int NT = K >> 5;

    const int arow = tid >> 2;
    const int scb = ((tid & 3) << 4) ^ ((arow & 6) << 3);
    const unsigned short* gA = A + (size_t)(brow + arow) * K + (scb >> 1);
    const unsigned short* gB = B + (size_t)(bcol + arow) * K + (scb >> 1);
    unsigned short* lA = lds + tid * 8;
    unsigned short* lB = lds + ASLOT + tid * 8;
    const size_t rows128 = (size_t)128 * K;

    auto stageA = [&](int kt, int slot) {
        const unsigned short* s = gA + ((size_t)kt << 5);
        unsigned short* d = lA + slot * SLOT;
        GLL(s, d);
        GLL(s + rows128, d + 4096);
    };
    auto stageB = [&](int kt, int slot) {
        const unsigned short* s = gB + ((size_t)kt << 5);
        unsigned short* d = lB + slot * SLOT;
#pragma unroll
        for (int h = 0; h < BISS; ++h)
            GLL(s + (size_t)h * rows128, d + h * 4096);
    };

    const int cbf = (((g << 4) ^ ((fm & 6) << 3)) >> 1);
    const unsigned short* fA = lds + (wm * (256 / WM) + fm) * 32 + cbf;
    const unsigned short* fB = lds + ASLOT + (wn * (BN / WN) + fm) * 32 + cbf;

    f32x4 acc[MREP][NREP] = {};

#pragma unroll
    for (int p = 0; p < DEPTH; ++p) { stageA(p, p); stageB(p, p); }
    asm volatile("s_waitcnt vmcnt(%0)" :: "n"((DEPTH - 1) * TISS) : "memory");
    __builtin_amdgcn_s_barrier();

    for (int t = 0; t < NT; ++t) {
        const int slot = t % NSLOT;
        const unsigned short* sA = fA + slot * SLOT;
        const unsigned short* sB = fB + slot * SLOT;
        const int pslot = (t + DEPTH) % NSLOT;
        const bool pf = (t + DEPTH) < NT;

        bf16x8 bfr[NREP];
        bf16x8 afr[4];
#pragma unroll
        for (int i = 0; i < 4; ++i) afr[i] = *(const bf16x8*)(sA + i * 512);
#pragma unroll
        for (int j = 0; j < NREP; ++j) bfr[j] = *(const bf16x8*)(sB + j * 512);
        if (pf) {
            stageA(t + DEPTH, pslot);
            if (PHASES == 1) stageB(t + DEPTH, pslot);
        }
        __builtin_amdgcn_s_barrier();
        asm volatile("s_waitcnt lgkmcnt(0)" ::: "memory");
        __builtin_amdgcn_s_setprio(1);
#pragma unroll
        for (int i = 0; i < 4; ++i)
#pragma unroll
            for (int j = 0; j < NREP; ++j)
                acc[i][j] = __builtin_amdgcn_mfma_f32_16x16x32_bf16(afr[i], bfr[j], acc[i][j], 0, 0, 0);
        __builtin_amdgcn_s_setprio(0);
        __builtin_amdgcn_s_barrier();

        if (PHASES == 2) {
#pragma unroll
            for (int i = 0; i < 4; ++i) afr[i] = *(const bf16x8*)(sA + (i + 4) * 512);
            if (pf) stageB(t + DEPTH, pslot);
            __builtin_amdgcn_s_barrier();
            asm volatile("s_waitcnt lgkmcnt(0)" ::: "memory");
            __builtin_amdgcn_s_setprio(1);
#pragma unroll
            for (int i = 0; i < 4; ++i)
#pragma unroll
                for (int j = 0; j < NREP; ++j)
                    acc[(i + 4) % MREP][j] = __builtin_amdgcn_mfma_f32_16x16x32_bf16(afr[i], bfr[j], acc[(i + 4) % MREP][j], 0, 0, 0);
            __builtin_amdgcn_s_setprio(0);
        }

        if (t + 1 < NT) {
            if (t + DEPTH < NT)
                asm volatile("s_waitcnt vmcnt(%0)" :: "n"(TISS) : "memory");
            else
                asm volatile("s_waitcnt vmcnt(0)" ::: "memory");
        }
        __builtin_amdgcn_s_barrier();
    }

    const int r0 = g << 2;
#pragma unroll
    for (int i = 0; i < MREP; ++i)
#pragma unroll
        for (int j = 0; j < NREP; ++j) {
            int col = bcol + wn * (BN / WN) + j * 16 + fm;
            float badd = bias ? bias[col] : 0.0f;
#pragma unroll
            for (int r = 0; r < 4; ++r) {
                int row = brow + wm * (256 / WM) + i * 16 + r0 + r;
                C[(size_t)row * N + col] = acc[i][j][r] * scale + badd;
            }
        }
}

extern "C" void kernel_launch(void* const* d_in, const int* in_sizes, int n_in,
                              void* d_out, int out_size, void* d_ws, size_t ws_size,
                              hipStream_t stream) {
    const float* x     = (const float*)d_in[0];
    const float* Wq    = (const float*)d_in[1];
    const float* bq    = (const float*)d_in[2];
    const float* gq    = (const float*)d_in[3];
    const float* betaq = (const float*)d_in[4];
    const float* Wk    = (const float*)d_in[5];
    const float* bk    = (const float*)d_in[6];
    const float* gk    = (const float*)d_in[7];
    const float* betak = (const float*)d_in[8];
    const float* Wv    = (const float*)d_in[9];
    const float* bv    = (const float*)d_in[10];
    const float* gv    = (const float*)d_in[11];
    const float* betav = (const float*)d_in[12];
    const float* Wo    = (const float*)d_in[13];
    const float* bo    = (const float*)d_in[14];
    const float* Wc    = (const float*)d_in[15];
    const float* bc    = (const float*)d_in[16];

    float* out_o    = (float*)d_out;
    float* out_c    = out_o + (size_t)S_SEQ * D_DIM;
    float* out_attn = out_c + (size_t)S_SEQ * NCLS;

    char* cur = (char*)d_ws;
    auto alloc = [&](size_t bytes) {
        char* p = cur;
        cur += (bytes + 255) & ~(size_t)255;
        return p;
    };
    const size_t SD2 = (size_t)S_SEQ * D_DIM * 2;
    const size_t DD2 = (size_t)D_DIM * D_DIM * 2;
    unsigned short* xb   = (unsigned short*)alloc(SD2);
    unsigned short* wqkv = (unsigned short*)alloc(3 * DD2);
    unsigned short* wto  = (unsigned short*)alloc(DD2);
    unsigned short* qb   = (unsigned short*)alloc(SD2);
    unsigned short* kb   = (unsigned short*)alloc(SD2);
    unsigned short* Vt   = (unsigned short*)alloc(SD2);
    unsigned short* valb = (unsigned short*)alloc(SD2);
    float* rmax   = (float*)alloc((size_t)S_SEQ * 4);
    float* rrecip = (float*)alloc((size_t)S_SEQ * 4);
    float* bqkv   = (float*)alloc((size_t)3 * D_DIM * 4);
    float* vstat  = (float*)alloc((size_t)S_SEQ * 2 * 4);
    float* pS     = (float*)alloc((size_t)S_SEQ * 48 * 4);
    float* pQ     = (float*)alloc((size_t)S_SEQ * 48 * 4);
    unsigned short* At = (unsigned short*)alloc((size_t)S_SEQ * S_SEQ * 2);
    unsigned short* Lb = (unsigned short*)alloc((size_t)S_SEQ * S_SEQ * 2);

    // overlays: QK^T softmax partial stats over xb (dead after QKV GEMM);
    // split-K partial over qb+kb (dead after QK^T; 32 MB exactly).
    float* pmax = (float*)xb;
    float* psum = pmax + (size_t)S_SEQ * 128;
    float* part1 = (float*)qb;
    // QKV bf16 z lives in the (not-yet-written) attention output region.
    unsigned short* zb = (unsigned short*)out_attn;

    const int n4_xd = S_SEQ * D_DIM / 4;

    // fused x->bf16 cast + classifier (reads x once)
    k_cast_classify<<<S_SEQ, 256, 0, stream>>>(x, Wc, bc, xb, out_c);
    // all 4 weight transposes in one launch
    k_transpose4<<<dim3(16, 16, 4), 256, 0, stream>>>(Wq, Wk, Wv, Wo, wqkv, wto);
    k_concat3<<<12, 256, 0, stream>>>(bq, bk, bv, bqkv);

    // fused QKV GEMM (8-phase, EPI=3): bf16 z + bias + LN partial sums
    k_gemm_8ph<1, 3><<<(S_SEQ / 256) * (3 * D_DIM / 256), 512, 0, stream>>>(
        xb, wqkv, nullptr, nullptr, zb, S_SEQ, 3 * D_DIM, D_DIM, 1.0f, bqkv, pS, pQ);
    // LN apply q/k + V-stats
    k_ln_apply_qk<<<S_SEQ, 256, 0, stream>>>(zb, pS, pQ, gq, betaq, gk, betak, qb, kb, vstat);
    // LN-V + transpose directly from zb -> Vt
    k_transpose_lnv<<<dim3(S_SEQ / 64, D_DIM / 64), 256, 0, stream>>>(zb, vstat, gv, betav, Vt);

    // logits = q k^T / 32 -> bf16 Lb (persistent 8-phase), fused softmax stats
    k_qkt_8ph<<<256, 512, 0, stream>>>(qb, kb, Lb, 0.03125f, pmax, psum);

    // combine stats, then normalize -> fp32 attention output + bf16 At
    k_stats_reduce<<<S_SEQ / 4, 256, 0, stream>>>(pmax, psum, rmax, rrecip, S_SEQ / 64);
    k_norm_transpose<<<dim3(S_SEQ / 64, S_SEQ / 64), 256, 0, stream>>>(
        Lb, out_attn, rmax, rrecip, At);

    // values = A^T V (8-phase, split-K=2: sk0 -> out_o scratch, sk1 -> part1), sum -> bf16
    k_gemm_8ph<2, 0><<<2 * (S_SEQ / 256) * (D_DIM / 256), 512, 0, stream>>>(
        At, Vt, out_o, part1, nullptr, S_SEQ, D_DIM, S_SEQ, 1.0f, nullptr, nullptr, nullptr);
    k_sum2_bf16<<<n4_xd / 256, 256, 0, stream>>>(out_o, part1, valb, n4_xd);

    // o = values @ Wo + bo (old structure)
    k_gemm_big<128, 4, 2, 3><<<(S_SEQ / 256) * (D_DIM / 128), 512, 0, stream>>>(
        valb, wto, out_o, S_SEQ, D_DIM, D_DIM, 1.0f, bo);
}